// Round 1
// baseline (358.810 us; speedup 1.0000x reference)
//
#include <hip/hip_runtime.h>

// Problem constants (fixed by setup_inputs)
constexpr int Bc = 2, Dc = 48, Hc = 512, Wc = 640;
constexpr int HWc = Hc * Wc;

// Tile config: 64x8 spatial tile, one thread per pixel, loop over D.
constexpr int TW = 64, TH = 8;
constexpr int HALO = 4;                      // max tap reach (far taps = +/-4)
constexpr int SW = TW + 2 * HALO;            // 72
constexpr int SH = TH + 2 * HALO;            // 16
constexpr int NT = TW * TH;                  // 512 threads
constexpr int NSTAGE = SW * SH;              // 1152 staged x-values per d
constexpr int NSIT = (NSTAGE + NT - 1) / NT; // 3 staging iters (2.25 avg)

__global__ __launch_bounds__(NT) void dw_kernel(
    const float* __restrict__ ds, const float* __restrict__ dmin,
    const float* __restrict__ dmax, const float* __restrict__ off,
    const float* __restrict__ scale_p, float* __restrict__ out)
{
    __shared__ float sx[2][NSTAGE];          // double-buffered x tile (9.2 KB)

    const int b   = blockIdx.z;
    const int h0  = blockIdx.y * TH;
    const int w0  = blockIdx.x * TW;
    const int tid = threadIdx.x;
    const int tw  = tid & (TW - 1);          // lane -> w within tile (wave = one row)
    const int th  = tid >> 6;
    const int h   = h0 + th;
    const int w   = w0 + tw;

    const float inv_min   = 1.0f / dmin[b];
    const float inv_max   = 1.0f / dmax[b];
    const float invd      = 1.0f / (inv_min - inv_max);
    const float inv_scale = 1.0f / scale_p[0];

    // 18 offset taps -> registers, reused for all 48 d-slices.
    float offF[9], offN[9];
    {
        const float* op = off + (size_t)b * 18 * HWc + (size_t)h * Wc + w;
        #pragma unroll
        for (int s = 0; s < 9; s++) {
            offF[s] = op[(size_t)s * HWc];        // far-range weights (channels 0..8)
            offN[s] = op[(size_t)(s + 9) * HWc];  // near-range weights (channels 9..17)
        }
    }

    // Precompute reflect-mapped global plane offsets for staging (d-invariant).
    int gidx[NSIT];
    #pragma unroll
    for (int i = 0; i < NSIT; i++) {
        int idx = tid + i * NT;
        if (idx < NSTAGE) {
            int r = idx / SW, c = idx - r * SW;
            int hs = h0 + r - HALO;
            int ws = w0 + c - HALO;
            hs = hs < 0 ? -hs : (hs >= Hc ? 2 * (Hc - 1) - hs : hs);
            ws = ws < 0 ? -ws : (ws >= Wc ? 2 * (Wc - 1) - ws : ws);
            gidx[i] = hs * Wc + ws;
        } else {
            gidx[i] = 0;
        }
    }

    const float* dsb  = ds  + (size_t)b * Dc * HWc;
    float*       outb = out + (size_t)b * Dc * HWc + (size_t)h * Wc + w;
    const int lbase = (th + HALO) * SW + (tw + HALO);

    for (int d = 0; d < Dc; d++) {
        float* sb = sx[d & 1];
        const float* dsp = dsb + (size_t)d * HWc;
        #pragma unroll
        for (int i = 0; i < NSIT; i++) {
            int idx = tid + i * NT;
            if (idx < NSTAGE) {                   // wave-uniform (128-thread boundary)
                float v = dsp[gidx[i]];
                sb[idx] = (__builtin_amdgcn_rcpf(v) - inv_max) * invd;
            }
        }
        __syncthreads();                          // single barrier (double-buffered)

        float x0  = sb[lbase];
        float acc = 0.0f;
        #pragma unroll
        for (int s = 0; s < 9; s++) {
            const int dy = (s / 3) * 2 - 2;       // {-2, 0, +2}
            const int dx = (s % 3) * 2 - 2;
            float xn = sb[lbase + dy * SW + dx];              // near tap (+/-2)
            float xf = sb[lbase + 2 * dy * SW + 2 * dx];      // far tap (+/-4)
            acc += offN[s] * xn + offF[s] * xf;
        }
        acc *= 0.5f;

        float x1 = fabsf(acc - x0) * inv_scale;
        x1 = fminf(x1, 4.0f);
        float t = 4.0f - 2.0f * x1;               // (2 - x1) * 2
        float r = __builtin_amdgcn_rcpf(1.0f + __expf(-t));   // sigmoid(t)
        outb[(size_t)d * HWc] = r;
    }
}

extern "C" void kernel_launch(void* const* d_in, const int* in_sizes, int n_in,
                              void* d_out, int out_size, void* d_ws, size_t ws_size,
                              hipStream_t stream) {
    const float* ds   = (const float*)d_in[0];  // depth_sample [B,D,H,W]
    const float* dmin = (const float*)d_in[1];  // depth_min [B]
    const float* dmax = (const float*)d_in[2];  // depth_max [B]
    const float* off  = (const float*)d_in[3];  // offset [B,18,H,W]
    const float* sc   = (const float*)d_in[4];  // patchmatch_interval_scale
    float* out = (float*)d_out;                 // [B,D,H,W] fp32

    dim3 grid(Wc / TW, Hc / TH, Bc);            // (10, 64, 2) — exact tiling
    dw_kernel<<<grid, NT, 0, stream>>>(ds, dmin, dmax, off, sc, out);
}

// Round 2
// 303.530 us; speedup vs baseline: 1.1821x; 1.1821x over previous
//
#include <hip/hip_runtime.h>

// Problem constants (fixed by setup_inputs)
constexpr int Bc = 2, Dc = 48, Hc = 512, Wc = 640;
constexpr int HWc = Hc * Wc;

// Tile: 64x16 spatial, 512 threads, 2 pixels/thread (rows th and th+8).
constexpr int TW = 64, TH = 16;
constexpr int NT = 512;
constexpr int HALO = 4;                      // far taps reach +/-4
constexpr int SW = TW + 2 * HALO;            // 72 (= 18 float4 per row)
constexpr int SH = TH + 2 * HALO;            // 24
constexpr int DC = 3;                        // d-planes per barrier interval
constexpr int NIT = Dc / DC;                 // 16 intervals
constexpr int PLANE = SW * SH;               // 1728 floats per plane
constexpr int NVEC = (PLANE / 4) * DC;       // 1296 float4 per interval
constexpr int VPT = (NVEC + NT - 1) / NT;    // 3 vec-loads/thread (last partial)
constexpr int NSCAL = PLANE * DC;            // 5184 scalars per interval
constexpr int SPT = (NSCAL + NT - 1) / NT;   // 11 (last iter = exactly 1 wave)

__device__ __forceinline__ int reflect_h(int h) {
    return h < 0 ? -h : (h >= Hc ? 2 * (Hc - 1) - h : h);
}
__device__ __forceinline__ int reflect_w(int w) {
    return w < 0 ? -w : (w >= Wc ? 2 * (Wc - 1) - w : w);
}

// 41.5 KB LDS, __launch_bounds__(512,6): 3 blocks/CU = 24 waves -> all 640
// blocks co-resident (no tail round).
__global__ __launch_bounds__(NT, 6) void dw_kernel(
    const float* __restrict__ ds, const float* __restrict__ dmin,
    const float* __restrict__ dmax, const float* __restrict__ off,
    const float* __restrict__ scale_p, float* __restrict__ out)
{
    __shared__ float sx[2][DC * PLANE];      // double-buffered (41.5 KB)

    const int b   = blockIdx.z;
    const int h0  = blockIdx.y * TH;
    const int w0  = blockIdx.x * TW;
    const int tid = threadIdx.x;
    const int tw  = tid & 63;                // wave = one 64-wide row
    const int th  = tid >> 6;                // 0..7

    const float inv_min   = 1.0f / dmin[b];
    const float inv_max   = 1.0f / dmax[b];
    const float invd      = 1.0f / (inv_min - inv_max);
    const float inv_scale = 1.0f / scale_p[0];

    // 2 pixels x 18 offset taps -> registers, reused across all 48 d.
    float offF[2][9], offN[2][9];
    #pragma unroll
    for (int px = 0; px < 2; ++px) {
        const float* op = off + (size_t)b * 18 * HWc
                        + (size_t)(h0 + th + px * 8) * Wc + (w0 + tw);
        #pragma unroll
        for (int s = 0; s < 9; ++s) {
            offF[px][s] = op[(size_t)s * HWc];        // far weights (ch 0..8)
            offN[px][s] = op[(size_t)(s + 9) * HWc];  // near weights (ch 9..17)
        }
    }

    const float* dsb  = ds  + (size_t)b * Dc * HWc;
    float*       outb = out + (size_t)b * Dc * HWc
                            + (size_t)(h0 + th) * Wc + (w0 + tw);

    // Stencil + epilogue for one interval, reading LDS buffer sb.
    auto compute = [&](const float* sb, int d0) {
        #pragma unroll
        for (int p = 0; p < DC; ++p) {
            #pragma unroll
            for (int px = 0; px < 2; ++px) {
                const float* base = sb + p * PLANE
                                  + (th + px * 8 + HALO) * SW + (tw + HALO);
                float x0  = base[0];
                float acc = 0.0f;
                #pragma unroll
                for (int s = 0; s < 9; ++s) {
                    const int dy = (s / 3) * 2 - 2;   // {-2,0,+2}
                    const int dx = (s % 3) * 2 - 2;
                    acc += offN[px][s] * base[dy * SW + dx];          // near
                    acc += offF[px][s] * base[2 * dy * SW + 2 * dx];  // far
                }
                acc *= 0.5f;
                float x1 = fminf(fabsf(acc - x0) * inv_scale, 4.0f);
                float t  = 4.0f - 2.0f * x1;
                outb[(size_t)(d0 + p) * HWc + px * 8 * Wc] =
                    __builtin_amdgcn_rcpf(1.0f + __expf(-t));
            }
        }
    };

    // w-reflect only touches the first/last block column; others vectorize.
    const bool interior = (blockIdx.x > 0) && (blockIdx.x + 1 < gridDim.x);

    if (interior) {
        // ---- float4 staging path ----
        int vsrc[VPT];                       // d-invariant source offsets
        #pragma unroll
        for (int i = 0; i < VPT; ++i) {
            int vid = tid + i * NT;
            if (vid < NVEC) {
                int p   = vid / (PLANE / 4);
                int rem = vid - p * (PLANE / 4);
                int r   = rem / (SW / 4);
                int j   = rem - r * (SW / 4);
                int hs  = reflect_h(h0 + r - HALO);
                vsrc[i] = p * HWc + hs * Wc + (w0 - HALO + 4 * j); // 16B-aligned
            } else vsrc[i] = 0;
        }
        float4 pre[VPT];
        auto issue = [&](int d0) {           // loads only -> stay in flight
            const float* dp = dsb + (size_t)d0 * HWc;
            #pragma unroll
            for (int i = 0; i < VPT; ++i) {
                int vid = tid + i * NT;
                if (vid < NVEC) pre[i] = *(const float4*)(dp + vsrc[i]);
            }
        };
        auto commit = [&](float* sb) {       // rcp-normalize + LDS write
            #pragma unroll
            for (int i = 0; i < VPT; ++i) {
                int vid = tid + i * NT;
                if (vid < NVEC) {
                    float4 v = pre[i], x;
                    x.x = (__builtin_amdgcn_rcpf(v.x) - inv_max) * invd;
                    x.y = (__builtin_amdgcn_rcpf(v.y) - inv_max) * invd;
                    x.z = (__builtin_amdgcn_rcpf(v.z) - inv_max) * invd;
                    x.w = (__builtin_amdgcn_rcpf(v.w) - inv_max) * invd;
                    *(float4*)(sb + vid * 4) = x;  // flat: vid*4 == dest index
                }
            }
        };
        issue(0);
        commit(sx[0]);
        __syncthreads();
        for (int it = 0; it < NIT; ++it) {
            if (it + 1 < NIT) issue((it + 1) * DC);   // prefetch under compute
            compute(sx[it & 1], it * DC);
            if (it + 1 < NIT) commit(sx[(it + 1) & 1]);
            __syncthreads();                          // one barrier/interval
        }
    } else {
        // ---- scalar staging path (w-edge blocks, 2 of 10 columns) ----
        int ssrc[SPT];
        #pragma unroll
        for (int i = 0; i < SPT; ++i) {
            int idx = tid + i * NT;
            if (idx < NSCAL) {
                int p   = idx / PLANE;
                int rem = idx - p * PLANE;
                int r   = rem / SW;
                int c   = rem - r * SW;
                int hs  = reflect_h(h0 + r - HALO);
                int ws  = reflect_w(w0 + c - HALO);
                ssrc[i] = p * HWc + hs * Wc + ws;
            } else ssrc[i] = 0;
        }
        float pre[SPT];
        auto issue = [&](int d0) {
            const float* dp = dsb + (size_t)d0 * HWc;
            #pragma unroll
            for (int i = 0; i < SPT; ++i) {
                int idx = tid + i * NT;
                if (idx < NSCAL) pre[i] = dp[ssrc[i]];
            }
        };
        auto commit = [&](float* sb) {
            #pragma unroll
            for (int i = 0; i < SPT; ++i) {
                int idx = tid + i * NT;
                if (idx < NSCAL)
                    sb[idx] = (__builtin_amdgcn_rcpf(pre[i]) - inv_max) * invd;
            }
        };
        issue(0);
        commit(sx[0]);
        __syncthreads();
        for (int it = 0; it < NIT; ++it) {
            if (it + 1 < NIT) issue((it + 1) * DC);
            compute(sx[it & 1], it * DC);
            if (it + 1 < NIT) commit(sx[(it + 1) & 1]);
            __syncthreads();
        }
    }
}

extern "C" void kernel_launch(void* const* d_in, const int* in_sizes, int n_in,
                              void* d_out, int out_size, void* d_ws, size_t ws_size,
                              hipStream_t stream) {
    const float* ds   = (const float*)d_in[0];  // depth_sample [B,D,H,W]
    const float* dmin = (const float*)d_in[1];  // depth_min [B]
    const float* dmax = (const float*)d_in[2];  // depth_max [B]
    const float* off  = (const float*)d_in[3];  // offset [B,18,H,W]
    const float* sc   = (const float*)d_in[4];  // patchmatch_interval_scale
    float* out = (float*)d_out;                 // [B,D,H,W] fp32

    dim3 grid(Wc / TW, Hc / TH, Bc);            // (10, 32, 2) = 640 blocks
    dw_kernel<<<grid, NT, 0, stream>>>(ds, dmin, dmax, off, sc, out);
}

// Round 3
// 270.432 us; speedup vs baseline: 1.3268x; 1.1224x over previous
//
#include <hip/hip_runtime.h>

// Problem constants (fixed by setup_inputs)
constexpr int Bc = 2, Dc = 48, Hc = 512, Wc = 640;
constexpr int HWc = Hc * Wc;

// Tile: 64x16 spatial, 256 threads, 4 consecutive-w pixels per thread.
constexpr int TW = 64, TH = 16, NT = 256;
constexpr int HALO = 4;                       // far taps reach +/-4
constexpr int SW = TW + 2 * HALO;             // 72 (18 float4 per row)
constexpr int SH = TH + 2 * HALO;             // 24
constexpr int PLANE = SW * SH;                // 1728 floats/plane
constexpr int DC = 2;                         // d-planes per barrier interval
constexpr int DSPLIT = 2;                     // d split across blocks (balance)
constexpr int DCHUNK = Dc / DSPLIT;           // 24 planes per block
constexpr int NIT = DCHUNK / DC;              // 12 intervals
constexpr int NVEC = DC * PLANE / 4;          // 864 float4 per interval
constexpr int VPT = (NVEC + NT - 1) / NT;     // 4
constexpr int NSC = DC * PLANE;               // 3456 scalars per interval
constexpr int SPT = (NSC + NT - 1) / NT;      // 14

__device__ __forceinline__ int reflect_h(int h) {
    return h < 0 ? -h : (h >= Hc ? 2 * (Hc - 1) - h : h);
}
__device__ __forceinline__ int reflect_w(int w) {
    return w < 0 ? -w : (w >= Wc ? 2 * (Wc - 1) - w : w);
}

// LDS = 27.6 KB -> >=5 blocks/CU even with coarse LDS granularity.
__global__ __launch_bounds__(NT) void dw_kernel(
    const float* __restrict__ ds, const float* __restrict__ dmin,
    const float* __restrict__ dmax, const float* __restrict__ off,
    const float* __restrict__ scale_p, float* __restrict__ out)
{
    __shared__ float sx[2][DC * PLANE];       // double-buffered (27648 B)

    const int bz   = blockIdx.z;              // b*2 + dchunk
    const int b    = bz >> 1;
    const int dch  = bz & 1;
    const int h0   = blockIdx.y * TH;
    const int w0   = blockIdx.x * TW;
    const int tid  = threadIdx.x;
    const int col4 = tid & 15;                // 16 float4-groups across 64 w
    const int row  = tid >> 4;                // 0..15

    const float inv_min   = 1.0f / dmin[b];
    const float inv_max   = 1.0f / dmax[b];
    const float invd      = 1.0f / (inv_min - inv_max);
    const float inv_scale = 1.0f / scale_p[0];

    // 18 offset channels x 4 pixels -> registers (float4 loads), reused 24x.
    float offF[9][4], offN[9][4];
    {
        const float* op = off + (size_t)b * 18 * HWc
                        + (size_t)(h0 + row) * Wc + (w0 + 4 * col4);
        #pragma unroll
        for (int s = 0; s < 9; ++s) {
            float4 vF = *(const float4*)(op + (size_t)s * HWc);
            float4 vN = *(const float4*)(op + (size_t)(s + 9) * HWc);
            offF[s][0] = vF.x; offF[s][1] = vF.y; offF[s][2] = vF.z; offF[s][3] = vF.w;
            offN[s][0] = vN.x; offN[s][1] = vN.y; offN[s][2] = vN.z; offN[s][3] = vN.w;
        }
    }

    const float* dsb  = ds  + ((size_t)b * Dc + dch * DCHUNK) * HWc;
    float*       outb = out + (size_t)b * Dc * HWc
                            + (size_t)(h0 + row) * Wc + (w0 + 4 * col4);
    const int dg0 = dch * DCHUNK;             // global d of this block's chunk

    // Stencil for one interval. Per plane: 15 ds_read_b128 feed 4 pixels.
    auto compute = [&](const float* sb, int dglob0) {
        #pragma unroll
        for (int p = 0; p < DC; ++p) {
            // base -> plane col 4*col4 == pixel col -4 (16B aligned)
            const float* base = sb + p * PLANE + (row + HALO) * SW + 4 * col4;
            float acc[4] = {0.f, 0.f, 0.f, 0.f};
            float x0[4], rb[12];
            auto ld12 = [&](const float* q) {
                *(float4*)(rb)     = *(const float4*)(q);
                *(float4*)(rb + 4) = *(const float4*)(q + 4);
                *(float4*)(rb + 8) = *(const float4*)(q + 8);
            };
            ld12(base - 4 * SW);              // dy=-4: far row sy=0
            #pragma unroll
            for (int j = 0; j < 4; ++j)
                acc[j] += offF[0][j]*rb[j] + offF[1][j]*rb[j+4] + offF[2][j]*rb[j+8];
            ld12(base - 2 * SW);              // dy=-2: near row sy=0
            #pragma unroll
            for (int j = 0; j < 4; ++j)
                acc[j] += offN[0][j]*rb[j+2] + offN[1][j]*rb[j+4] + offN[2][j]*rb[j+6];
            ld12(base);                       // dy=0: near+far sy=1, center
            #pragma unroll
            for (int j = 0; j < 4; ++j) {
                x0[j] = rb[j + 4];
                acc[j] += offN[3][j]*rb[j+2] + offN[4][j]*rb[j+4] + offN[5][j]*rb[j+6]
                        + offF[3][j]*rb[j]   + offF[4][j]*rb[j+4] + offF[5][j]*rb[j+8];
            }
            ld12(base + 2 * SW);              // dy=+2: near row sy=2
            #pragma unroll
            for (int j = 0; j < 4; ++j)
                acc[j] += offN[6][j]*rb[j+2] + offN[7][j]*rb[j+4] + offN[8][j]*rb[j+6];
            ld12(base + 4 * SW);              // dy=+4: far row sy=2
            #pragma unroll
            for (int j = 0; j < 4; ++j)
                acc[j] += offF[6][j]*rb[j] + offF[7][j]*rb[j+4] + offF[8][j]*rb[j+8];

            float4 o; float* po = (float*)&o;
            #pragma unroll
            for (int j = 0; j < 4; ++j) {
                float a  = 0.5f * acc[j];
                float x1 = fminf(fabsf(a - x0[j]) * inv_scale, 4.0f);
                float t  = 4.0f - 2.0f * x1;
                po[j] = __builtin_amdgcn_rcpf(1.0f + __expf(-t));
            }
            *(float4*)(outb + (size_t)(dglob0 + p) * HWc) = o;
        }
    };

    // w-reflect only touches first/last block column; others vectorize.
    const bool interior = (blockIdx.x > 0) && (blockIdx.x + 1 < gridDim.x);

    if (interior) {
        int vsrc[VPT];                        // d-invariant source offsets
        #pragma unroll
        for (int i = 0; i < VPT; ++i) {
            int vid = tid + i * NT;
            if (vid < NVEC) {
                int p   = vid / (PLANE / 4);
                int rem = vid - p * (PLANE / 4);
                int r   = rem / (SW / 4);
                int j   = rem - r * (SW / 4);
                int hs  = reflect_h(h0 + r - HALO);
                vsrc[i] = p * HWc + hs * Wc + (w0 - HALO + 4 * j);
            } else vsrc[i] = 0;
        }
        float4 pre[VPT];
        auto issue = [&](int d0) {            // loads only -> in flight under compute
            const float* dp = dsb + (size_t)d0 * HWc;
            #pragma unroll
            for (int i = 0; i < VPT; ++i) {
                int vid = tid + i * NT;
                if (vid < NVEC) pre[i] = *(const float4*)(dp + vsrc[i]);
            }
        };
        auto commit = [&](float* sb) {
            #pragma unroll
            for (int i = 0; i < VPT; ++i) {
                int vid = tid + i * NT;
                if (vid < NVEC) {
                    float4 v = pre[i], x;
                    x.x = (__builtin_amdgcn_rcpf(v.x) - inv_max) * invd;
                    x.y = (__builtin_amdgcn_rcpf(v.y) - inv_max) * invd;
                    x.z = (__builtin_amdgcn_rcpf(v.z) - inv_max) * invd;
                    x.w = (__builtin_amdgcn_rcpf(v.w) - inv_max) * invd;
                    *(float4*)(sb + vid * 4) = x;
                }
            }
        };
        issue(0);
        commit(sx[0]);
        __syncthreads();
        for (int it = 0; it < NIT; ++it) {
            if (it + 1 < NIT) issue((it + 1) * DC);
            compute(sx[it & 1], dg0 + it * DC);
            if (it + 1 < NIT) commit(sx[(it + 1) & 1]);
            __syncthreads();
        }
    } else {
        int ssrc[SPT];                        // scalar path (w-edge blocks)
        #pragma unroll
        for (int i = 0; i < SPT; ++i) {
            int idx = tid + i * NT;
            if (idx < NSC) {
                int p   = idx / PLANE;
                int rem = idx - p * PLANE;
                int r   = rem / SW;
                int c   = rem - r * SW;
                int hs  = reflect_h(h0 + r - HALO);
                int ws  = reflect_w(w0 + c - HALO);
                ssrc[i] = p * HWc + hs * Wc + ws;
            } else ssrc[i] = 0;
        }
        float pre[SPT];
        auto issue = [&](int d0) {
            const float* dp = dsb + (size_t)d0 * HWc;
            #pragma unroll
            for (int i = 0; i < SPT; ++i) {
                int idx = tid + i * NT;
                if (idx < NSC) pre[i] = dp[ssrc[i]];
            }
        };
        auto commit = [&](float* sb) {
            #pragma unroll
            for (int i = 0; i < SPT; ++i) {
                int idx = tid + i * NT;
                if (idx < NSC)
                    sb[idx] = (__builtin_amdgcn_rcpf(pre[i]) - inv_max) * invd;
            }
        };
        issue(0);
        commit(sx[0]);
        __syncthreads();
        for (int it = 0; it < NIT; ++it) {
            if (it + 1 < NIT) issue((it + 1) * DC);
            compute(sx[it & 1], dg0 + it * DC);
            if (it + 1 < NIT) commit(sx[(it + 1) & 1]);
            __syncthreads();
        }
    }
}

extern "C" void kernel_launch(void* const* d_in, const int* in_sizes, int n_in,
                              void* d_out, int out_size, void* d_ws, size_t ws_size,
                              hipStream_t stream) {
    const float* ds   = (const float*)d_in[0];  // depth_sample [B,D,H,W]
    const float* dmin = (const float*)d_in[1];  // depth_min [B]
    const float* dmax = (const float*)d_in[2];  // depth_max [B]
    const float* off  = (const float*)d_in[3];  // offset [B,18,H,W]
    const float* sc   = (const float*)d_in[4];  // patchmatch_interval_scale
    float* out = (float*)d_out;                 // [B,D,H,W] fp32

    dim3 grid(Wc / TW, Hc / TH, Bc * DSPLIT);   // (10, 32, 4) = 1280 blocks = 5.0/CU
    dw_kernel<<<grid, NT, 0, stream>>>(ds, dmin, dmax, off, sc, out);
}